// Round 6
// baseline (274.338 us; speedup 1.0000x reference)
//
#include <hip/hip_runtime.h>

// RelMultiHeadSelfAttention (Transformer-XL) on gfx950.
// B=2, T=1024, M=1024, L=J=2048, D=1024, H=16, dh=64. fp32 in/out, bf16 MFMA inside.
//
// Pipeline: prep -> gemm_qkvr(merged) -> attn(K-split x2) -> combine -> gemm_out.
// Rel-shift: p = j+1023-i: p<=2047 -> qv[i].r[p]; p==2048 -> 0; p>=2049 -> qv[i+1].r[p-2049].
// SCALE*log2(e) folded into qu/qv so softmax runs in exp2 domain.
//
// R1: XCD swizzle: FETCH 102->16.5 MB, dur flat -> not bandwidth/L3-latency bound.
// R2: launch_bounds(256,4) -> VGPR coerced, 2.3 GB spill. Reverted.
// R3: K-split @ (256,2): flat -> per-wave chain-bound (~16.7K cyc/tile).
// R4: constant-max softmax + fragment-major K/V/r: attn 217 -> 114.5us.
// R5: U [row][84] layout (conflicts 6.4M->2.1M), P-overlay (LDS 21.5KB),
//     merged qkvr. attn 108.7us = 8.2K cyc/tile per-wave chain; occupancy
//     null at halved LDS -> duration IS the chain. FETCH ~= unique footprint
//     -> first-touch HBM latency (~900cy) embedded ~3x per tile.
// R6: T14 pipeline: prefetch next tile's K(8)+r(10) frags into a second
//     register set right after current QK (manually 2x-unrolled, named A/B
//     sets, static indexing); V issued at body top. Leak tail stays inline.

typedef unsigned short u16;
typedef unsigned int u32;
typedef short bf16x8 __attribute__((ext_vector_type(8)));
typedef float f32x4 __attribute__((ext_vector_type(4)));

#define MFMA16(a, b, c) __builtin_amdgcn_mfma_f32_16x16x32_bf16(a, b, c, 0, 0, 0)

__device__ __forceinline__ u16 f2bf(float f) {  // RNE fp32 -> bf16
  u32 u = __float_as_uint(f);
  u32 r = (u + 0x7fffu + ((u >> 16) & 1u)) >> 16;
  return (u16)r;
}

__device__ __forceinline__ void async16(void* lds, const void* g) {
  __builtin_amdgcn_global_load_lds(
      (const __attribute__((address_space(1))) u32*)g,
      (__attribute__((address_space(3))) u32*)lds, 16, 0, 0);
}

// ---------------- prep: fp32 -> bf16 conversions -----------------------------
__global__ void prep_kernel(const float* __restrict__ x, const float* __restrict__ mem,
                            const float* __restrict__ pos,
                            const float* __restrict__ qw, const float* __restrict__ kw,
                            const float* __restrict__ vw, const float* __restrict__ rw,
                            const float* __restrict__ ow,
                            u16* __restrict__ catb, u16* __restrict__ posb,
                            u16* __restrict__ wqb, u16* __restrict__ wkb,
                            u16* __restrict__ wvb, u16* __restrict__ wrb,
                            u16* __restrict__ wob) {
  const int seg = blockIdx.y;
  const int vid = blockIdx.x * blockDim.x + threadIdx.x;
  const float* src = nullptr;
  u16* dst = nullptr;
  int count = 0;
  switch (seg) {
    case 0: count = (2 * 2048 * 1024) / 4; dst = catb; break;
    case 1: count = (2048 * 1024) / 4; src = pos; dst = posb; break;
    case 2: count = (1024 * 1024) / 4; src = qw; dst = wqb; break;
    case 3: count = (1024 * 1024) / 4; src = kw; dst = wkb; break;
    case 4: count = (1024 * 1024) / 4; src = vw; dst = wvb; break;
    case 5: count = (1024 * 1024) / 4; src = rw; dst = wrb; break;
    case 6: count = (1024 * 1024) / 4; src = ow; dst = wob; break;
  }
  if (vid >= count) return;
  float4 f;
  if (seg == 0) {
    int e = vid * 4;                 // element index into cat [2][2048][1024]
    int col = e & 1023;
    int row = (e >> 10) & 2047;      // time position within cat
    int b = e >> 21;
    const float* s2 = (row < 1024)
                          ? (mem + ((size_t)(b * 1024 + row) * 1024 + col))
                          : (x + ((size_t)(b * 1024 + (row - 1024)) * 1024 + col));
    f = *(const float4*)s2;
  } else {
    f = *(const float4*)(src + (size_t)vid * 4);
  }
  ushort4 o4;
  o4.x = f2bf(f.x); o4.y = f2bf(f.y); o4.z = f2bf(f.z); o4.w = f2bf(f.w);
  *(ushort4*)(dst + (size_t)vid * 4) = o4;
}

// ---------------- GEMM core: C[128x128] = A[128xK] * W[128xK]^T, K=1024 ------
__device__ __forceinline__ void gemm_core(const u16* __restrict__ A, const u16* __restrict__ W,
                                          u16* As, u16* Bs, int m0, int n0, bool qmap,
                                          f32x4 acc[4][4]) {
  const int t = threadIdx.x;
  const int lane = t & 63, wid = t >> 6;
  const int colL = lane & 15, rg = lane >> 4;
  const int wm = (wid >> 1) * 64, wn = (wid & 1) * 64;
  for (int kt = 0; kt < 32; ++kt) {
    __syncthreads();
#pragma unroll
    for (int pass = 0; pass < 2; ++pass) {
      int slot = t + pass * 256;      // 0..511 -> 128 rows x 4 16B-chunks
      int row = slot >> 2, ch = slot & 3;
      int sch = ch ^ ((row >> 1) & 3);
      int ar = m0 + row;
      if (qmap) ar = ((ar >> 10) << 11) + 1024 + (ar & 1023);  // q rows live inside cat
      async16(As + slot * 8, A + (size_t)ar * 1024 + kt * 32 + sch * 8);
      async16(Bs + slot * 8, W + (size_t)(n0 + row) * 1024 + kt * 32 + sch * 8);
    }
    __syncthreads();
    bf16x8 af[4], bfr[4];
#pragma unroll
    for (int mi = 0; mi < 4; ++mi) {
      int r = wm + mi * 16 + colL;
      af[mi] = *(const bf16x8*)(As + r * 32 + (rg ^ ((r >> 1) & 3)) * 8);
    }
#pragma unroll
    for (int ni = 0; ni < 4; ++ni) {
      int r = wn + ni * 16 + colL;
      bfr[ni] = *(const bf16x8*)(Bs + r * 32 + (rg ^ ((r >> 1) & 3)) * 8);
    }
#pragma unroll
    for (int mi = 0; mi < 4; ++mi)
#pragma unroll
      for (int ni = 0; ni < 4; ++ni)
        acc[mi][ni] = MFMA16(af[mi], bfr[ni], acc[mi][ni]);
  }
}

// ---------------- merged q+r+k+v projections (768 blocks) ----------------
__global__ __launch_bounds__(256, 2) void gemm_qkvr(
    const u16* __restrict__ catb, const u16* __restrict__ posb,
    const u16* __restrict__ wqb, const u16* __restrict__ wrb,
    const u16* __restrict__ wkb, const u16* __restrict__ wvb,
    const float* __restrict__ bu, const float* __restrict__ bv,
    u16* __restrict__ qub, u16* __restrict__ qvb, u16* __restrict__ rbuf,
    u16* __restrict__ kbuf, u16* __restrict__ vtbuf) {
  __shared__ u16 As[128 * 32], Bs[128 * 32];
  const int x = blockIdx.x;
  const int bid = (x & 7) * 96 + (x >> 3);   // XCD swizzle over 768 (768%8==0)
  const u16* A;
  const u16* W;
  int mode, r2;
  bool qmap = false;
  if (bid < 128)      { mode = 0; A = catb; W = wqb; qmap = true; r2 = bid; }
  else if (bid < 256) { mode = 1; A = posb; W = wrb; r2 = bid - 128; }
  else if (bid < 512) { mode = 2; A = catb; W = wkb; r2 = bid - 256; }
  else                { mode = 3; A = catb; W = wvb; r2 = bid - 512; }
  const int m0 = (r2 >> 3) * 128, n0 = (r2 & 7) * 128;
  f32x4 acc[4][4];
  f32x4 zz = {0.f, 0.f, 0.f, 0.f};
#pragma unroll
  for (int a1 = 0; a1 < 4; ++a1)
#pragma unroll
    for (int a2 = 0; a2 < 4; ++a2) acc[a1][a2] = zz;
  gemm_core(A, W, As, Bs, m0, n0, qmap, acc);
  const int t = threadIdx.x, lane = t & 63, wid = t >> 6;
  const int colL = lane & 15, rg = lane >> 4;
  const int wm = (wid >> 1) * 64, wn = (wid & 1) * 64;
  const float sc = 0.18033688f;  // 0.125 * log2(e)
#pragma unroll
  for (int mi = 0; mi < 4; ++mi)
#pragma unroll
    for (int ni = 0; ni < 4; ++ni)
#pragma unroll
      for (int e = 0; e < 4; ++e) {
        int m = m0 + wm + mi * 16 + rg * 4 + e;
        int n = n0 + wn + ni * 16 + colL;
        float val = acc[mi][ni][e];
        int hh = n >> 6, dd = n & 63;
        if (mode == 0) {
          int bb = m >> 10, tq = m & 1023;
          size_t ad = (((size_t)(bb * 16 + hh)) * 1024 + tq) * 64 + dd;
          qub[ad] = f2bf((val + bu[n]) * sc);
          qvb[ad] = f2bf((val + bv[n]) * sc);
        } else if (mode == 1) {
          rbuf[((((size_t)hh * 128 + (m >> 4)) * 8 + (dd >> 3)) * 16 + (m & 15)) * 8 +
               (dd & 7)] = f2bf(val);
        } else {
          int bb = m >> 11, j = m & 2047;
          size_t bh2 = (size_t)(bb * 16 + hh);
          if (mode == 2)
            kbuf[(((bh2 * 128 + (j >> 4)) * 8 + (dd >> 3)) * 16 + (j & 15)) * 8 + (dd & 7)] =
                f2bf(val);
          else
            vtbuf[((((bh2 * 32 + (j >> 6)) * 4 + (dd >> 4)) * 8 + ((j >> 3) & 7)) * 16 +
                   (dd & 15)) * 8 + (j & 7)] = f2bf(val);
        }
      }
}

// ---------------- fused rel-pos flash attention (K-split x2, pipelined) ------
// One tile body. kc/rc: current tile's K/r frags (already loaded).
// kn/rn: filled with next tile's frags, issued right after QK (kc dead).
__device__ __forceinline__ void attn_body(
    const int jt, const int jn, const int i0, const int colL, const int rg,
    const int lane8, const u16* __restrict__ kb, const u16* __restrict__ vb,
    const u16* __restrict__ rb, const u16* __restrict__ qvb,
    const bf16x8 aqu[2], const bf16x8 aqv[2], const bf16x8& ones,
    bf16x8 kc[8], bf16x8 rc[10], bf16x8 kn[8], bf16x8 rn[10],
    f32x4 o[4], f32x4& lacc, const int lb[4], float* Uw, u16* Pw) {
  const f32x4 zz = {0.f, 0.f, 0.f, 0.f};
  const int j0 = jt * 64;
  // ---- content scores from current (prefetched) K frags ----
  f32x4 s[4];
#pragma unroll
  for (int ni = 0; ni < 4; ++ni) {
    s[ni] = zz;
    s[ni] = MFMA16(aqu[0], kc[2 * ni], s[ni]);
    s[ni] = MFMA16(aqu[1], kc[2 * ni + 1], s[ni]);
  }
  // ---- prefetch next tile K + r (kc dead now; consumed next body) ----
  {
    const int jn0 = jn * 64;
#pragma unroll
    for (int ni = 0; ni < 4; ++ni) {
      const u16* kp = kb + (size_t)((jn0 >> 4) + ni) * 1024 + lane8;
      kn[2 * ni] = *(const bf16x8*)kp;
      kn[2 * ni + 1] = *(const bf16x8*)(kp + 512);
    }
    const int tbn = (jn0 + 1008 - i0) >> 4;
#pragma unroll
    for (int uc = 0; uc < 5; ++uc) {
      int tt = tbn + uc;
      tt = tt < 127 ? tt : 127;  // clamp; out-of-range rows discarded at gather
      tt = tt > 0 ? tt : 0;
      const u16* rp = rb + (size_t)tt * 1024 + lane8;
      rn[2 * uc] = *(const bf16x8*)(rp);
      rn[2 * uc + 1] = *(const bf16x8*)(rp + 512);
    }
  }
  // ---- V loads for this tile (consumed at PV, ~bottom of body) ----
  bf16x8 vf[8];
  {
    const u16* vp0 = vb + (size_t)jt * 4096 + lane8;
#pragma unroll
    for (int ni = 0; ni < 4; ++ni) {
      vf[2 * ni] = *(const bf16x8*)(vp0 + ni * 1024);
      vf[2 * ni + 1] = *(const bf16x8*)(vp0 + ni * 1024 + 512);
    }
  }
  const int pbase = j0 + 1008 - i0;  // min p in tile - 15; 16-aligned
  const bool mainv = (pbase <= 2047);
  const bool leak = (pbase + 78 >= 2049);
  if (mainv) {
    // U[row][idx] = qv[i0+row] . r[pbase+idx] from prefetched rc frags
#pragma unroll
    for (int uc = 0; uc < 5; ++uc) {
      f32x4 ua = zz;
      ua = MFMA16(aqv[0], rc[2 * uc], ua);
      ua = MFMA16(aqv[1], rc[2 * uc + 1], ua);
#pragma unroll
      for (int e = 0; e < 4; ++e) Uw[(rg * 4 + e) * 84 + uc * 16 + colL] = ua[e];
    }
    asm volatile("s_waitcnt lgkmcnt(0)" ::: "memory");
    const int pl = pbase + colL + 15;
#pragma unroll
    for (int c = 0; c < 4; ++c)
#pragma unroll
      for (int e = 0; e < 4; ++e) {
        float uval = Uw[lb[e] + c * 16];
        int p = pl + c * 16 - (rg * 4 + e);
        s[c][e] += (p <= 2047) ? uval : 0.f;
      }
  }
  if (leak) {  // rare tail tiles (ks==1 only); inline loads, serial is OK
    asm volatile("s_waitcnt lgkmcnt(0)" ::: "memory");
    bf16x8 aqs0, aqs1;  // qv row+1, loaded lazily
    {
      int r0 = i0 + colL;
      int rs = (r0 + 1 < 1024) ? r0 + 1 : 1023;
      aqs0 = *(const bf16x8*)(qvb + (size_t)rs * 64 + rg * 8);
      aqs1 = *(const bf16x8*)(qvb + (size_t)rs * 64 + 32 + rg * 8);
    }
    // rows p-2049: per-lane tile/row select (pb2 == 15 mod 16)
    const int mB1 = (pbase - 2048) >> 4;
    const int rowL = (colL + 15) & 15;
    const int tadj = (colL > 0) ? 0 : -1;
#pragma unroll
    for (int uc = 0; uc < 5; ++uc) {
      int tL = mB1 + uc + tadj;
      tL = tL < 0 ? 0 : (tL > 127 ? 127 : tL);  // clamp; OOR discarded at gather
      const u16* rp = rb + (size_t)tL * 1024 + rg * 128 + rowL * 8;
      f32x4 ua = zz;
      ua = MFMA16(aqs0, *(const bf16x8*)rp, ua);
      ua = MFMA16(aqs1, *(const bf16x8*)(rp + 512), ua);
#pragma unroll
      for (int e = 0; e < 4; ++e) Uw[(rg * 4 + e) * 84 + uc * 16 + colL] = ua[e];
    }
    asm volatile("s_waitcnt lgkmcnt(0)" ::: "memory");
    const int pl = pbase + colL + 15;
#pragma unroll
    for (int c = 0; c < 4; ++c)
#pragma unroll
      for (int e = 0; e < 4; ++e) {
        int p = pl + c * 16 - (rg * 4 + e);
        if (p >= 2049) s[c][e] += Uw[lb[e] + c * 16];
      }
  }
  // ---- constant-max softmax: P = exp2(s - 16); no cross-lane reduce ----
#pragma unroll
  for (int c = 0; c < 4; ++c)
#pragma unroll
    for (int e = 0; e < 4; ++e) {
      float px = __builtin_amdgcn_exp2f(s[c][e] - 16.0f);
      int row = rg * 4 + e;
      int col = c * 16 + colL;
      int sw = (col >> 3) ^ (row & 7);
      Pw[row * 64 + sw * 8 + (col & 7)] = f2bf(px);
    }
  asm volatile("s_waitcnt lgkmcnt(0)" ::: "memory");
  bf16x8 pa[2];
#pragma unroll
  for (int kx = 0; kx < 2; ++kx) {
    int chunk = kx * 4 + rg;
    int sw = chunk ^ (colL & 7);
    pa[kx] = *(const bf16x8*)(Pw + colL * 64 + sw * 8);
  }
  // ---- row-sums l via ones-MFMA; O += P @ V ----
  lacc = MFMA16(pa[0], ones, lacc);
  lacc = MFMA16(pa[1], ones, lacc);
#pragma unroll
  for (int ni = 0; ni < 4; ++ni) {
    o[ni] = MFMA16(pa[0], vf[2 * ni], o[ni]);
    o[ni] = MFMA16(pa[1], vf[2 * ni + 1], o[ni]);
  }
  asm volatile("" ::: "memory");  // keep LDS WAR ordering across tiles
}

// 1024 blocks x 256 thr; wave = 16 q-rows of one (b,h), 16 key-tiles.
__global__ __launch_bounds__(256, 2) void attn_kernel(
    const u16* __restrict__ qu, const u16* __restrict__ qv, const u16* __restrict__ ktile,
    const u16* __restrict__ vtile, const u16* __restrict__ rtile,
    float* __restrict__ opart, float* __restrict__ mlpart) {
  __shared__ float Ulds[4][16 * 84];  // 5376 B/wave; P (bf16, 2048 B) overlaid
  const int t = threadIdx.x;
  const int wid = t >> 6, lane = t & 63;
  const int colL = lane & 15, rg = lane >> 4;
  // XCD swizzle: 32 consecutive blocks (one full bh) per XCD.
  const int bid = ((blockIdx.x & 7) << 7) | (blockIdx.x >> 3);
  const int bh = bid >> 5;                    // 0..31
  const int rem = bid & 31;
  const int qc = rem >> 1, ks = rem & 1;      // q-chunk (16), K-half (2)
  const int h = bh & 15;
  const int i0 = qc * 64 + wid * 16;          // wave's q-row base

  const u16* qub = qu + (size_t)bh * (1024 * 64);
  const u16* qvb = qv + (size_t)bh * (1024 * 64);
  const u16* kb = ktile + (size_t)bh * (128 * 1024);
  const u16* vb = vtile + (size_t)bh * (32 * 4096);
  const u16* rb = rtile + (size_t)h * (128 * 1024);
  const int lane8 = (rg * 16 + colL) * 8;     // coalesced frag offset (elements)

  bf16x8 aqu[2], aqv[2];
  {
    int r0 = i0 + colL;
#pragma unroll
    for (int kx = 0; kx < 2; ++kx) {
      aqu[kx] = *(const bf16x8*)(qub + (size_t)r0 * 64 + kx * 32 + rg * 8);
      aqv[kx] = *(const bf16x8*)(qvb + (size_t)r0 * 64 + kx * 32 + rg * 8);
    }
  }
  bf16x8 ones;
#pragma unroll
  for (int i = 0; i < 8; ++i) ones[i] = (short)0x3F80;  // bf16 1.0

  const f32x4 zz = {0.f, 0.f, 0.f, 0.f};
  f32x4 o[4];
  f32x4 lacc = zz;
#pragma unroll
  for (int e = 0; e < 4; ++e) o[e] = zz;
  // U gather base: addr(c,e) = lb[e] + c*16  (row*84 + idx, idx = c*16+colL-row+15)
  int lb[4];
#pragma unroll
  for (int e = 0; e < 4; ++e) lb[e] = (rg * 4 + e) * 83 + colL + 15;

  float* Uw = &Ulds[wid][0];
  u16* Pw = (u16*)Uw;  // P overlays U (2048 B of 5376)

  const int jt0 = ks * 16;
  // ---- prologue: load tile jt0's K + r frags into set A ----
  bf16x8 kA[8], rA[10], kB[8], rB[10];
  {
    const int j0 = jt0 * 64;
#pragma unroll
    for (int ni = 0; ni < 4; ++ni) {
      const u16* kp = kb + (size_t)((j0 >> 4) + ni) * 1024 + lane8;
      kA[2 * ni] = *(const bf16x8*)kp;
      kA[2 * ni + 1] = *(const bf16x8*)(kp + 512);
    }
    const int tb = (j0 + 1008 - i0) >> 4;
#pragma unroll
    for (int uc = 0; uc < 5; ++uc) {
      int tt = tb + uc;
      tt = tt < 127 ? tt : 127;
      tt = tt > 0 ? tt : 0;
      const u16* rp = rb + (size_t)tt * 1024 + lane8;
      rA[2 * uc] = *(const bf16x8*)rp;
      rA[2 * uc + 1] = *(const bf16x8*)(rp + 512);
    }
  }
  // ---- 8 pipelined tile-pairs (A/B register ping-pong, static indexing) ----
#pragma unroll 1
  for (int p = 0; p < 8; ++p) {
    const int jt = jt0 + 2 * p;
    attn_body(jt, jt + 1, i0, colL, rg, lane8, kb, vb, rb, qvb, aqu, aqv, ones,
              kA, rA, kB, rB, o, lacc, lb, Uw, Pw);
    const int jn2 = (p < 7) ? jt + 2 : jt0;  // wrap keeps prefetch in-bounds
    attn_body(jt + 1, jn2, i0, colL, rg, lane8, kb, vb, rb, qvb, aqu, aqv, ones,
              kB, rB, kA, rA, o, lacc, lb, Uw, Pw);
  }
  // ---- write fp32 partials (no division; combine merges) ----
  const size_t rowbase = (size_t)ks * 32768 + (size_t)bh * 1024 + i0;
#pragma unroll
  for (int c = 0; c < 4; ++c)
#pragma unroll
    for (int e = 0; e < 4; ++e) {
      int row = rg * 4 + e;
      opart[(rowbase + row) * 64 + c * 16 + colL] = o[c][e];
    }
  if (colL == 0) {
#pragma unroll
    for (int e = 0; e < 4; ++e) {
      size_t r = rowbase + rg * 4 + e;
      mlpart[r * 2 + 0] = 16.0f;      // constant max (exp2 domain)
      mlpart[r * 2 + 1] = lacc[e];
    }
  }
}

// ---------------- combine: merge the two K-halves ----------------
__global__ void combine_kernel(const float* __restrict__ opart,
                               const float* __restrict__ mlpart,
                               u16* __restrict__ aout) {
  const int gid = blockIdx.x * 256 + threadIdx.x;   // 524288
  const int r = gid >> 4;                            // 0..32767 = bh*1024 + i
  const int cg = gid & 15;
  float2 ml0 = *(const float2*)(mlpart + (size_t)r * 2);
  float2 ml1 = *(const float2*)(mlpart + ((size_t)32768 + r) * 2);
  float m = fmaxf(ml0.x, ml1.x);
  float f0 = __builtin_amdgcn_exp2f(ml0.x - m);
  float f1 = __builtin_amdgcn_exp2f(ml1.x - m);
  float inv = 1.0f / (ml0.y * f0 + ml1.y * f1);
  f0 *= inv; f1 *= inv;
  float4 a = *(const float4*)(opart + (size_t)r * 64 + cg * 4);
  float4 b4 = *(const float4*)(opart + ((size_t)32768 + r) * 64 + cg * 4);
  ushort4 o4;
  o4.x = f2bf(a.x * f0 + b4.x * f1);
  o4.y = f2bf(a.y * f0 + b4.y * f1);
  o4.z = f2bf(a.z * f0 + b4.z * f1);
  o4.w = f2bf(a.w * f0 + b4.w * f1);
  const int bh = r >> 10, i = r & 1023;
  const int b = bh >> 4, h = bh & 15;
  *(ushort4*)(aout + ((size_t)(b * 1024 + i) * 1024 + h * 64 + cg * 4)) = o4;
}

// ---------------- output projection ----------------
__global__ __launch_bounds__(256, 2) void gemm_out(
    const u16* __restrict__ aob, const u16* __restrict__ wob, float* __restrict__ out) {
  __shared__ u16 As[128 * 32], Bs[128 * 32];
  const int bid = ((blockIdx.x & 7) << 4) | (blockIdx.x >> 3);  // XCD swizzle (128 blocks)
  const int mt = bid >> 3, nt = bid & 7;
  const int m0 = mt * 128, n0 = nt * 128;
  f32x4 acc[4][4];
  f32x4 zz = {0.f, 0.f, 0.f, 0.f};
#pragma unroll
  for (int a1 = 0; a1 < 4; ++a1)
#pragma unroll
    for (int a2 = 0; a2 < 4; ++a2) acc[a1][a2] = zz;
  gemm_core(aob, wob, As, Bs, m0, n0, false, acc);
  const int t = threadIdx.x, lane = t & 63, wid = t >> 6;
  const int colL = lane & 15, rg = lane >> 4;
  const int wm = (wid >> 1) * 64, wn = (wid & 1) * 64;
#pragma unroll
  for (int mi = 0; mi < 4; ++mi)
#pragma unroll
    for (int ni = 0; ni < 4; ++ni)
#pragma unroll
      for (int e = 0; e < 4; ++e) {
        int m = m0 + wm + mi * 16 + rg * 4 + e;
        int n = n0 + wn + ni * 16 + colL;
        out[(size_t)m * 1024 + n] = acc[mi][ni][e];
      }
}

// ---------------- host ----------------
extern "C" void kernel_launch(void* const* d_in, const int* in_sizes, int n_in,
                              void* d_out, int out_size, void* d_ws, size_t ws_size,
                              hipStream_t stream) {
  (void)in_sizes; (void)n_in; (void)out_size; (void)ws_size;
  const float* x = (const float*)d_in[0];
  const float* mem = (const float*)d_in[1];
  const float* pos = (const float*)d_in[2];
  const float* qw = (const float*)d_in[3];
  const float* kw = (const float*)d_in[4];
  const float* vw = (const float*)d_in[5];
  const float* rw = (const float*)d_in[6];
  const float* ow = (const float*)d_in[7];
  const float* bu = (const float*)d_in[8];
  const float* bv = (const float*)d_in[9];
  float* out = (float*)d_out;

  char* w = (char*)d_ws;
  u16* catb = (u16*)(w + 0);          //  8 MB  (dead after gemm_qkvr)
  u16* posb = (u16*)(w + 8388608);    //  4 MB  (dead after gemm_qkvr)
  u16* wqb  = (u16*)(w + 12582912);   //  2 MB
  u16* wkb  = (u16*)(w + 14680064);   //  2 MB
  u16* wvb  = (u16*)(w + 16777216);   //  2 MB
  u16* wrb  = (u16*)(w + 18874368);   //  2 MB
  u16* wob  = (u16*)(w + 20971520);   //  2 MB  (live until gemm_out)
  u16* qub  = (u16*)(w + 23068672);   //  4 MB  [B*H][1024][64]
  u16* qvb  = (u16*)(w + 27262976);   //  4 MB  [B*H][1024][64]
  u16* kbuf = (u16*)(w + 31457280);   //  8 MB  ktile [B*H][128][8][16][8]
  u16* vtb  = (u16*)(w + 39845888);   //  8 MB  vtile [B*H][32][4][8][16][8]
  u16* rbuf = (u16*)(w + 48234496);   //  4 MB  rA    [H][128][8][16][8]
  u16* aob  = (u16*)(w + 52428800);   //  4 MB  [B*T][1024]
  // K-split partials overlay dead prep buffers:
  float* opart  = (float*)(w + 0);         // 16 MB  [2][32768][64] fp32
  float* mlpart = (float*)(w + 16777216);  // 512 KB [2][32768][2]  fp32

  prep_kernel<<<dim3(4096, 7), 256, 0, stream>>>(x, mem, pos, qw, kw, vw, rw, ow,
                                                 catb, posb, wqb, wkb, wvb, wrb, wob);
  gemm_qkvr<<<768, 256, 0, stream>>>(catb, posb, wqb, wrb, wkb, wvb, bu, bv,
                                     qub, qvb, rbuf, kbuf, vtb);
  attn_kernel<<<1024, 256, 0, stream>>>(qub, qvb, kbuf, vtb, rbuf, opart, mlpart);
  combine_kernel<<<2048, 256, 0, stream>>>(opart, mlpart, aob);
  gemm_out<<<128, 256, 0, stream>>>(aob, wob, out);
}

// Round 7
// 226.194 us; speedup vs baseline: 1.2128x; 1.2128x over previous
//
#include <hip/hip_runtime.h>

// RelMultiHeadSelfAttention (Transformer-XL) on gfx950.
// B=2, T=1024, M=1024, L=J=2048, D=1024, H=16, dh=64. fp32 in/out, bf16 MFMA inside.
//
// Pipeline: prep -> gemm_qkvr(merged) -> attn(K-split x2) -> combine -> gemm_out.
// Rel-shift: p = j+1023-i: p<=2047 -> qv[i].r[p]; p==2048 -> 0; p>=2049 -> qv[i+1].r[p-2049].
// SCALE*log2(e) folded into qu/qv so softmax runs in exp2 domain.
//
// R1: XCD swizzle: FETCH 102->16.5 MB, dur flat -> not bandwidth/L3-latency bound.
// R2: launch_bounds(256,4) -> VGPR coerced, 2.3 GB spill; occupancy 39% though.
// R3: K-split @ (256,2): flat -> per-wave chain-bound.
// R4: constant-max softmax + fragment-major K/V/r: attn 217 -> 114.5us.
// R5: U [row][84], P-overlay, merged qkvr: attn 108.7us.
// R6: K/r reg-prefetch: VGPR 68->128, attn 119us (WORSE). Load latency is NOT
//     the chain driver (confirms R1 null); registers cost residency.
// R7: occupancy is granule-capped at 2 waves/SIMD (total arch+acc VGPR in the
//     129-256 bin; m69). So spend the granule: 32 q-rows per wave (two 16-row
//     MFMA blocks). K/V/r loads + 3 LDS drains/tile amortize over 2x rows and
//     the body carries 2x independent MFMA chains for the 2 resident waves.
//     512 blocks = exactly 2/CU, one batch. U scratch [32][100] f32 (51.2 KB),
//     P overlays. No prefetch (R6 reverted).

typedef unsigned short u16;
typedef unsigned int u32;
typedef short bf16x8 __attribute__((ext_vector_type(8)));
typedef float f32x4 __attribute__((ext_vector_type(4)));

#define MFMA16(a, b, c) __builtin_amdgcn_mfma_f32_16x16x32_bf16(a, b, c, 0, 0, 0)

__device__ __forceinline__ u16 f2bf(float f) {  // RNE fp32 -> bf16
  u32 u = __float_as_uint(f);
  u32 r = (u + 0x7fffu + ((u >> 16) & 1u)) >> 16;
  return (u16)r;
}

__device__ __forceinline__ void async16(void* lds, const void* g) {
  __builtin_amdgcn_global_load_lds(
      (const __attribute__((address_space(1))) u32*)g,
      (__attribute__((address_space(3))) u32*)lds, 16, 0, 0);
}

// ---------------- prep: fp32 -> bf16 conversions -----------------------------
__global__ void prep_kernel(const float* __restrict__ x, const float* __restrict__ mem,
                            const float* __restrict__ pos,
                            const float* __restrict__ qw, const float* __restrict__ kw,
                            const float* __restrict__ vw, const float* __restrict__ rw,
                            const float* __restrict__ ow,
                            u16* __restrict__ catb, u16* __restrict__ posb,
                            u16* __restrict__ wqb, u16* __restrict__ wkb,
                            u16* __restrict__ wvb, u16* __restrict__ wrb,
                            u16* __restrict__ wob) {
  const int seg = blockIdx.y;
  const int vid = blockIdx.x * blockDim.x + threadIdx.x;
  const float* src = nullptr;
  u16* dst = nullptr;
  int count = 0;
  switch (seg) {
    case 0: count = (2 * 2048 * 1024) / 4; dst = catb; break;
    case 1: count = (2048 * 1024) / 4; src = pos; dst = posb; break;
    case 2: count = (1024 * 1024) / 4; src = qw; dst = wqb; break;
    case 3: count = (1024 * 1024) / 4; src = kw; dst = wkb; break;
    case 4: count = (1024 * 1024) / 4; src = vw; dst = wvb; break;
    case 5: count = (1024 * 1024) / 4; src = rw; dst = wrb; break;
    case 6: count = (1024 * 1024) / 4; src = ow; dst = wob; break;
  }
  if (vid >= count) return;
  float4 f;
  if (seg == 0) {
    int e = vid * 4;                 // element index into cat [2][2048][1024]
    int col = e & 1023;
    int row = (e >> 10) & 2047;      // time position within cat
    int b = e >> 21;
    const float* s2 = (row < 1024)
                          ? (mem + ((size_t)(b * 1024 + row) * 1024 + col))
                          : (x + ((size_t)(b * 1024 + (row - 1024)) * 1024 + col));
    f = *(const float4*)s2;
  } else {
    f = *(const float4*)(src + (size_t)vid * 4);
  }
  ushort4 o4;
  o4.x = f2bf(f.x); o4.y = f2bf(f.y); o4.z = f2bf(f.z); o4.w = f2bf(f.w);
  *(ushort4*)(dst + (size_t)vid * 4) = o4;
}

// ---------------- GEMM core: C[128x128] = A[128xK] * W[128xK]^T, K=1024 ------
__device__ __forceinline__ void gemm_core(const u16* __restrict__ A, const u16* __restrict__ W,
                                          u16* As, u16* Bs, int m0, int n0, bool qmap,
                                          f32x4 acc[4][4]) {
  const int t = threadIdx.x;
  const int lane = t & 63, wid = t >> 6;
  const int colL = lane & 15, rg = lane >> 4;
  const int wm = (wid >> 1) * 64, wn = (wid & 1) * 64;
  for (int kt = 0; kt < 32; ++kt) {
    __syncthreads();
#pragma unroll
    for (int pass = 0; pass < 2; ++pass) {
      int slot = t + pass * 256;      // 0..511 -> 128 rows x 4 16B-chunks
      int row = slot >> 2, ch = slot & 3;
      int sch = ch ^ ((row >> 1) & 3);
      int ar = m0 + row;
      if (qmap) ar = ((ar >> 10) << 11) + 1024 + (ar & 1023);  // q rows live inside cat
      async16(As + slot * 8, A + (size_t)ar * 1024 + kt * 32 + sch * 8);
      async16(Bs + slot * 8, W + (size_t)(n0 + row) * 1024 + kt * 32 + sch * 8);
    }
    __syncthreads();
    bf16x8 af[4], bfr[4];
#pragma unroll
    for (int mi = 0; mi < 4; ++mi) {
      int r = wm + mi * 16 + colL;
      af[mi] = *(const bf16x8*)(As + r * 32 + (rg ^ ((r >> 1) & 3)) * 8);
    }
#pragma unroll
    for (int ni = 0; ni < 4; ++ni) {
      int r = wn + ni * 16 + colL;
      bfr[ni] = *(const bf16x8*)(Bs + r * 32 + (rg ^ ((r >> 1) & 3)) * 8);
    }
#pragma unroll
    for (int mi = 0; mi < 4; ++mi)
#pragma unroll
      for (int ni = 0; ni < 4; ++ni)
        acc[mi][ni] = MFMA16(af[mi], bfr[ni], acc[mi][ni]);
  }
}

// ---------------- merged q+r+k+v projections (768 blocks) ----------------
__global__ __launch_bounds__(256, 2) void gemm_qkvr(
    const u16* __restrict__ catb, const u16* __restrict__ posb,
    const u16* __restrict__ wqb, const u16* __restrict__ wrb,
    const u16* __restrict__ wkb, const u16* __restrict__ wvb,
    const float* __restrict__ bu, const float* __restrict__ bv,
    u16* __restrict__ qub, u16* __restrict__ qvb, u16* __restrict__ rbuf,
    u16* __restrict__ kbuf, u16* __restrict__ vtbuf) {
  __shared__ u16 As[128 * 32], Bs[128 * 32];
  const int x = blockIdx.x;
  const int bid = (x & 7) * 96 + (x >> 3);   // XCD swizzle over 768 (768%8==0)
  const u16* A;
  const u16* W;
  int mode, r2;
  bool qmap = false;
  if (bid < 128)      { mode = 0; A = catb; W = wqb; qmap = true; r2 = bid; }
  else if (bid < 256) { mode = 1; A = posb; W = wrb; r2 = bid - 128; }
  else if (bid < 512) { mode = 2; A = catb; W = wkb; r2 = bid - 256; }
  else                { mode = 3; A = catb; W = wvb; r2 = bid - 512; }
  const int m0 = (r2 >> 3) * 128, n0 = (r2 & 7) * 128;
  f32x4 acc[4][4];
  f32x4 zz = {0.f, 0.f, 0.f, 0.f};
#pragma unroll
  for (int a1 = 0; a1 < 4; ++a1)
#pragma unroll
    for (int a2 = 0; a2 < 4; ++a2) acc[a1][a2] = zz;
  gemm_core(A, W, As, Bs, m0, n0, qmap, acc);
  const int t = threadIdx.x, lane = t & 63, wid = t >> 6;
  const int colL = lane & 15, rg = lane >> 4;
  const int wm = (wid >> 1) * 64, wn = (wid & 1) * 64;
  const float sc = 0.18033688f;  // 0.125 * log2(e)
#pragma unroll
  for (int mi = 0; mi < 4; ++mi)
#pragma unroll
    for (int ni = 0; ni < 4; ++ni)
#pragma unroll
      for (int e = 0; e < 4; ++e) {
        int m = m0 + wm + mi * 16 + rg * 4 + e;
        int n = n0 + wn + ni * 16 + colL;
        float val = acc[mi][ni][e];
        int hh = n >> 6, dd = n & 63;
        if (mode == 0) {
          int bb = m >> 10, tq = m & 1023;
          size_t ad = (((size_t)(bb * 16 + hh)) * 1024 + tq) * 64 + dd;
          qub[ad] = f2bf((val + bu[n]) * sc);
          qvb[ad] = f2bf((val + bv[n]) * sc);
        } else if (mode == 1) {
          rbuf[((((size_t)hh * 128 + (m >> 4)) * 8 + (dd >> 3)) * 16 + (m & 15)) * 8 +
               (dd & 7)] = f2bf(val);
        } else {
          int bb = m >> 11, j = m & 2047;
          size_t bh2 = (size_t)(bb * 16 + hh);
          if (mode == 2)
            kbuf[(((bh2 * 128 + (j >> 4)) * 8 + (dd >> 3)) * 16 + (j & 15)) * 8 + (dd & 7)] =
                f2bf(val);
          else
            vtbuf[((((bh2 * 32 + (j >> 6)) * 4 + (dd >> 4)) * 8 + ((j >> 3) & 7)) * 16 +
                   (dd & 15)) * 8 + (j & 7)] = f2bf(val);
        }
      }
}

// ---------------- fused rel-pos flash attention (K-split x2, 32 rows/wave) ---
// 512 blocks x 256 thr; wave = 32 q-rows (two 16-row MFMA blocks) of one (b,h),
// 16 key-tiles. K/V/r loads + drains shared by both row-blocks; 2x in-body ILP.
// Constant-max softmax (m=16); l via ones-MFMA. pbase2 = j0+992-i0 (16-aligned).
// Row-block0 (w=0..15): idx = c*16+colL+31-w, band uc 1..5.
// Row-block1 (w=16..31): idx = c*16+colL+15-(w-16), band uc 0..4.
__global__ __launch_bounds__(256, 2) void attn_kernel(
    const u16* __restrict__ qu, const u16* __restrict__ qv, const u16* __restrict__ ktile,
    const u16* __restrict__ vtile, const u16* __restrict__ rtile,
    float* __restrict__ opart, float* __restrict__ mlpart) {
  __shared__ float Ulds[4][3200];  // [32 rows][stride 100] f32 = 12.8 KB/wave
  const int t = threadIdx.x;
  const int wid = t >> 6, lane = t & 63;
  const int colL = lane & 15, rg = lane >> 4;
  // XCD swizzle: 16 consecutive blocks (one full bh) per XCD. 512 blocks.
  const int bid = ((blockIdx.x & 7) << 6) | (blockIdx.x >> 3);
  const int bh = bid >> 4;                    // 0..31
  const int rem = bid & 15;
  const int qc = rem >> 1, ks = rem & 1;      // q-chunk of 128 (8), K-half (2)
  const int h = bh & 15;
  const int i0 = qc * 128 + wid * 32;         // wave's q-row base (32 rows)

  const u16* qub = qu + (size_t)bh * (1024 * 64);
  const u16* qvb = qv + (size_t)bh * (1024 * 64);
  const u16* kb = ktile + (size_t)bh * (128 * 1024);
  const u16* vb = vtile + (size_t)bh * (32 * 4096);
  const u16* rb = rtile + (size_t)h * (128 * 1024);
  const int lane8 = (rg * 16 + colL) * 8;     // coalesced frag offset (elements)

  bf16x8 aqu0[2], aqv0[2], aqu1[2], aqv1[2];
  {
    int r0 = i0 + colL;           // row-block0 A-frag rows
    int r1 = i0 + 16 + colL;      // row-block1
#pragma unroll
    for (int kx = 0; kx < 2; ++kx) {
      aqu0[kx] = *(const bf16x8*)(qub + (size_t)r0 * 64 + kx * 32 + rg * 8);
      aqv0[kx] = *(const bf16x8*)(qvb + (size_t)r0 * 64 + kx * 32 + rg * 8);
      aqu1[kx] = *(const bf16x8*)(qub + (size_t)r1 * 64 + kx * 32 + rg * 8);
      aqv1[kx] = *(const bf16x8*)(qvb + (size_t)r1 * 64 + kx * 32 + rg * 8);
    }
  }
  bf16x8 ones;
#pragma unroll
  for (int i = 0; i < 8; ++i) ones[i] = (short)0x3F80;  // bf16 1.0

  const f32x4 zz = {0.f, 0.f, 0.f, 0.f};
  f32x4 o0[4], o1[4];
  f32x4 lacc0 = zz, lacc1 = zz;
#pragma unroll
  for (int e = 0; e < 4; ++e) { o0[e] = zz; o1[e] = zz; }
  // Gather bases: addr(c,e) = lb[e] + c*16
  // blk0: w*100 + (c*16+colL+31-w) = w*99 + colL+31
  // blk1: (16+w)*100 + (c*16+colL+15-w) = w*99 + 1615 + colL
  int lb0[4], lb1[4];
#pragma unroll
  for (int e = 0; e < 4; ++e) {
    lb0[e] = (rg * 4 + e) * 99 + colL + 31;
    lb1[e] = (rg * 4 + e) * 99 + colL + 1615;
  }

  float* Uw = &Ulds[wid][0];
  u16* Pw = (u16*)Uw;  // P (32x64 bf16 = 4 KB) overlays U

#pragma unroll 1
  for (int jt = ks * 16; jt < ks * 16 + 16; ++jt) {
    const int j0 = jt * 64;
    // ---- K frags + content scores for both row-blocks ----
    f32x4 s0[4], s1[4];
#pragma unroll
    for (int ni = 0; ni < 4; ++ni) {
      const u16* kp = kb + (size_t)((j0 >> 4) + ni) * 1024 + lane8;
      bf16x8 b0 = *(const bf16x8*)kp;
      bf16x8 b1 = *(const bf16x8*)(kp + 512);
      s0[ni] = zz;
      s0[ni] = MFMA16(aqu0[0], b0, s0[ni]);
      s0[ni] = MFMA16(aqu0[1], b1, s0[ni]);
      s1[ni] = zz;
      s1[ni] = MFMA16(aqu1[0], b0, s1[ni]);
      s1[ni] = MFMA16(aqu1[1], b1, s1[ni]);
    }
    const int pbase2 = j0 + 992 - i0;  // min p over tile; 16-aligned
    const bool mainv = (pbase2 <= 2047);
    const bool leak = (pbase2 + 94 >= 2049);
    if (mainv) {
      const int tb = pbase2 >> 4;
      bf16x8 rc[12];
#pragma unroll
      for (int uc = 0; uc < 6; ++uc) {
        int tt = tb + uc;
        tt = tt < 127 ? tt : 127;  // clamp; OOR values discarded at gather
        const u16* rp = rb + (size_t)tt * 1024 + lane8;
        rc[2 * uc] = *(const bf16x8*)rp;
        rc[2 * uc + 1] = *(const bf16x8*)(rp + 512);
      }
      // U MFMAs: blk0 band uc 1..5; blk1 band uc 0..4 (shared rc loads)
#pragma unroll
      for (int uc = 1; uc < 6; ++uc) {
        f32x4 ua = zz;
        ua = MFMA16(aqv0[0], rc[2 * uc], ua);
        ua = MFMA16(aqv0[1], rc[2 * uc + 1], ua);
#pragma unroll
        for (int e = 0; e < 4; ++e) Uw[(rg * 4 + e) * 100 + uc * 16 + colL] = ua[e];
      }
#pragma unroll
      for (int uc = 0; uc < 5; ++uc) {
        f32x4 ub = zz;
        ub = MFMA16(aqv1[0], rc[2 * uc], ub);
        ub = MFMA16(aqv1[1], rc[2 * uc + 1], ub);
#pragma unroll
        for (int e = 0; e < 4; ++e) Uw[(16 + rg * 4 + e) * 100 + uc * 16 + colL] = ub[e];
      }
      asm volatile("s_waitcnt lgkmcnt(0)" ::: "memory");
      const int pl0 = pbase2 + colL + 31;
      const int pl1 = pbase2 + colL + 15;
#pragma unroll
      for (int c = 0; c < 4; ++c)
#pragma unroll
        for (int e = 0; e < 4; ++e) {
          int w0e = rg * 4 + e;
          float u0 = Uw[lb0[e] + c * 16];
          float u1 = Uw[lb1[e] + c * 16];
          int p0 = pl0 + c * 16 - w0e;
          int p1 = pl1 + c * 16 - w0e;
          s0[c][e] += (p0 <= 2047) ? u0 : 0.f;
          s1[c][e] += (p1 <= 2047) ? u1 : 0.f;
        }
    }
    if (leak) {  // only ks==1 tiles; needs qv[i+1].r[p-2049] where p>=2049
      asm volatile("s_waitcnt lgkmcnt(0)" ::: "memory");
      bf16x8 aqs0[2], aqs1[2];
      {
        int rs0 = i0 + colL + 1;                       // <= 1008, no clamp needed
        int rs1 = i0 + 16 + colL + 1;
        rs1 = rs1 < 1024 ? rs1 : 1023;                 // clamp (row unused at i=1023)
#pragma unroll
        for (int kx = 0; kx < 2; ++kx) {
          aqs0[kx] = *(const bf16x8*)(qvb + (size_t)rs0 * 64 + kx * 32 + rg * 8);
          aqs1[kx] = *(const bf16x8*)(qvb + (size_t)rs1 * 64 + kx * 32 + rg * 8);
        }
      }
      // leak r rows: p-2049 = pb2 + idx, pb2 = pbase2-2049 == 15 (mod 16)
      const int mB1 = (pbase2 - 2048) >> 4;
      const int rowL = (colL + 15) & 15;
      const int tadj = (colL > 0) ? 0 : -1;
      bf16x8 r2[12];
#pragma unroll
      for (int uc = 0; uc < 6; ++uc) {
        int tL = mB1 + uc + tadj;
        tL = tL < 0 ? 0 : (tL > 127 ? 127 : tL);  // clamp; OOR discarded at gather
        const u16* rp = rb + (size_t)tL * 1024 + rg * 128 + rowL * 8;
        r2[2 * uc] = *(const bf16x8*)rp;
        r2[2 * uc + 1] = *(const bf16x8*)(rp + 512);
      }
#pragma unroll
      for (int uc = 1; uc < 6; ++uc) {
        f32x4 ua = zz;
        ua = MFMA16(aqs0[0], r2[2 * uc], ua);
        ua = MFMA16(aqs0[1], r2[2 * uc + 1], ua);
#pragma unroll
        for (int e = 0; e < 4; ++e) Uw[(rg * 4 + e) * 100 + uc * 16 + colL] = ua[e];
      }
#pragma unroll
      for (int uc = 0; uc < 5; ++uc) {
        f32x4 ub = zz;
        ub = MFMA16(aqs1[0], r2[2 * uc], ub);
        ub = MFMA16(aqs1[1], r2[2 * uc + 1], ub);
#pragma unroll
        for (int e = 0; e < 4; ++e) Uw[(16 + rg * 4 + e) * 100 + uc * 16 + colL] = ub[e];
      }
      asm volatile("s_waitcnt lgkmcnt(0)" ::: "memory");
      const int pl0 = pbase2 + colL + 31;
      const int pl1 = pbase2 + colL + 15;
#pragma unroll
      for (int c = 0; c < 4; ++c)
#pragma unroll
        for (int e = 0; e < 4; ++e) {
          int w0e = rg * 4 + e;
          int p0 = pl0 + c * 16 - w0e;
          int p1 = pl1 + c * 16 - w0e;
          if (p0 >= 2049) s0[c][e] += Uw[lb0[e] + c * 16];
          if (p1 >= 2049) s1[c][e] += Uw[lb1[e] + c * 16];
        }
    }
    // ---- V frag loads (shared by both row-blocks) ----
    bf16x8 vf[8];
    {
      const u16* vp0 = vb + (size_t)jt * 4096 + lane8;
#pragma unroll
      for (int ni = 0; ni < 4; ++ni) {
        vf[2 * ni] = *(const bf16x8*)(vp0 + ni * 1024);
        vf[2 * ni + 1] = *(const bf16x8*)(vp0 + ni * 1024 + 512);
      }
    }
    // ---- constant-max softmax: P = exp2(s - 16); write both row-blocks ----
#pragma unroll
    for (int c = 0; c < 4; ++c)
#pragma unroll
      for (int e = 0; e < 4; ++e) {
        int row = rg * 4 + e;
        int col = c * 16 + colL;
        int sw = (col >> 3) ^ (row & 7);  // (16+row)&7 == row&7: same sw for blk1
        float p0 = __builtin_amdgcn_exp2f(s0[c][e] - 16.0f);
        float p1 = __builtin_amdgcn_exp2f(s1[c][e] - 16.0f);
        Pw[row * 64 + sw * 8 + (colL & 7)] = f2bf(p0);
        Pw[(16 + row) * 64 + sw * 8 + (colL & 7)] = f2bf(p1);
      }
    asm volatile("s_waitcnt lgkmcnt(0)" ::: "memory");
    bf16x8 pa0[2], pa1[2];
#pragma unroll
    for (int kx = 0; kx < 2; ++kx) {
      int chunk = kx * 4 + rg;
      int sw = chunk ^ (colL & 7);
      pa0[kx] = *(const bf16x8*)(Pw + colL * 64 + sw * 8);
      pa1[kx] = *(const bf16x8*)(Pw + (16 + colL) * 64 + sw * 8);
    }
    // ---- row-sums via ones-MFMA; O += P @ V (both row-blocks, shared vf) ----
    lacc0 = MFMA16(pa0[0], ones, lacc0);
    lacc0 = MFMA16(pa0[1], ones, lacc0);
    lacc1 = MFMA16(pa1[0], ones, lacc1);
    lacc1 = MFMA16(pa1[1], ones, lacc1);
#pragma unroll
    for (int ni = 0; ni < 4; ++ni) {
      o0[ni] = MFMA16(pa0[0], vf[2 * ni], o0[ni]);
      o0[ni] = MFMA16(pa0[1], vf[2 * ni + 1], o0[ni]);
      o1[ni] = MFMA16(pa1[0], vf[2 * ni], o1[ni]);
      o1[ni] = MFMA16(pa1[1], vf[2 * ni + 1], o1[ni]);
    }
    asm volatile("" ::: "memory");  // keep LDS WAR ordering across tiles
  }
  // ---- write fp32 partials (no division; combine merges) ----
  const size_t rowbase = (size_t)ks * 32768 + (size_t)bh * 1024 + i0;
#pragma unroll
  for (int c = 0; c < 4; ++c)
#pragma unroll
    for (int e = 0; e < 4; ++e) {
      int row = rg * 4 + e;
      opart[(rowbase + row) * 64 + c * 16 + colL] = o0[c][e];
      opart[(rowbase + 16 + row) * 64 + c * 16 + colL] = o1[c][e];
    }
  if (colL == 0) {
#pragma unroll
    for (int e = 0; e < 4; ++e) {
      size_t r = rowbase + rg * 4 + e;
      mlpart[r * 2 + 0] = 16.0f;
      mlpart[r * 2 + 1] = lacc0[e];
      mlpart[(r + 16) * 2 + 0] = 16.0f;
      mlpart[(r + 16) * 2 + 1] = lacc1[e];
    }
  }
}

// ---------------- combine: merge the two K-halves ----------------
__global__ void combine_kernel(const float* __restrict__ opart,
                               const float* __restrict__ mlpart,
                               u16* __restrict__ aout) {
  const int gid = blockIdx.x * 256 + threadIdx.x;   // 524288
  const int r = gid >> 4;                            // 0..32767 = bh*1024 + i
  const int cg = gid & 15;
  float2 ml0 = *(const float2*)(mlpart + (size_t)r * 2);
  float2 ml1 = *(const float2*)(mlpart + ((size_t)32768 + r) * 2);
  float m = fmaxf(ml0.x, ml1.x);
  float f0 = __builtin_amdgcn_exp2f(ml0.x - m);
  float f1 = __builtin_amdgcn_exp2f(ml1.x - m);
  float inv = 1.0f / (ml0.y * f0 + ml1.y * f1);
  f0 *= inv; f1 *= inv;
  float4 a = *(const float4*)(opart + (size_t)r * 64 + cg * 4);
  float4 b4 = *(const float4*)(opart + ((size_t)32768 + r) * 64 + cg * 4);
  ushort4 o4;
  o4.x = f2bf(a.x * f0 + b4.x * f1);
  o4.y = f2bf(a.y * f0 + b4.y * f1);
  o4.z = f2bf(a.z * f0 + b4.z * f1);
  o4.w = f2bf(a.w * f0 + b4.w * f1);
  const int bh = r >> 10, i = r & 1023;
  const int b = bh >> 4, h = bh & 15;
  *(ushort4*)(aout + ((size_t)(b * 1024 + i) * 1024 + h * 64 + cg * 4)) = o4;
}

// ---------------- output projection ----------------
__global__ __launch_bounds__(256, 2) void gemm_out(
    const u16* __restrict__ aob, const u16* __restrict__ wob, float* __restrict__ out) {
  __shared__ u16 As[128 * 32], Bs[128 * 32];
  const int bid = ((blockIdx.x & 7) << 4) | (blockIdx.x >> 3);  // XCD swizzle (128 blocks)
  const int mt = bid >> 3, nt = bid & 7;
  const int m0 = mt * 128, n0 = nt * 128;
  f32x4 acc[4][4];
  f32x4 zz = {0.f, 0.f, 0.f, 0.f};
#pragma unroll
  for (int a1 = 0; a1 < 4; ++a1)
#pragma unroll
    for (int a2 = 0; a2 < 4; ++a2) acc[a1][a2] = zz;
  gemm_core(aob, wob, As, Bs, m0, n0, false, acc);
  const int t = threadIdx.x, lane = t & 63, wid = t >> 6;
  const int colL = lane & 15, rg = lane >> 4;
  const int wm = (wid >> 1) * 64, wn = (wid & 1) * 64;
#pragma unroll
  for (int mi = 0; mi < 4; ++mi)
#pragma unroll
    for (int ni = 0; ni < 4; ++ni)
#pragma unroll
      for (int e = 0; e < 4; ++e) {
        int m = m0 + wm + mi * 16 + rg * 4 + e;
        int n = n0 + wn + ni * 16 + colL;
        out[(size_t)m * 1024 + n] = acc[mi][ni][e];
      }
}

// ---------------- host ----------------
extern "C" void kernel_launch(void* const* d_in, const int* in_sizes, int n_in,
                              void* d_out, int out_size, void* d_ws, size_t ws_size,
                              hipStream_t stream) {
  (void)in_sizes; (void)n_in; (void)out_size; (void)ws_size;
  const float* x = (const float*)d_in[0];
  const float* mem = (const float*)d_in[1];
  const float* pos = (const float*)d_in[2];
  const float* qw = (const float*)d_in[3];
  const float* kw = (const float*)d_in[4];
  const float* vw = (const float*)d_in[5];
  const float* rw = (const float*)d_in[6];
  const float* ow = (const float*)d_in[7];
  const float* bu = (const float*)d_in[8];
  const float* bv = (const float*)d_in[9];
  float* out = (float*)d_out;

  char* w = (char*)d_ws;
  u16* catb = (u16*)(w + 0);          //  8 MB  (dead after gemm_qkvr)
  u16* posb = (u16*)(w + 8388608);    //  4 MB  (dead after gemm_qkvr)
  u16* wqb  = (u16*)(w + 12582912);   //  2 MB
  u16* wkb  = (u16*)(w + 14680064);   //  2 MB
  u16* wvb  = (u16*)(w + 16777216);   //  2 MB
  u16* wrb  = (u16*)(w + 18874368);   //  2 MB
  u16* wob  = (u16*)(w + 20971520);   //  2 MB  (live until gemm_out)
  u16* qub  = (u16*)(w + 23068672);   //  4 MB  [B*H][1024][64]
  u16* qvb  = (u16*)(w + 27262976);   //  4 MB  [B*H][1024][64]
  u16* kbuf = (u16*)(w + 31457280);   //  8 MB  ktile [B*H][128][8][16][8]
  u16* vtb  = (u16*)(w + 39845888);   //  8 MB  vtile [B*H][32][4][8][16][8]
  u16* rbuf = (u16*)(w + 48234496);   //  4 MB  rA    [H][128][8][16][8]
  u16* aob  = (u16*)(w + 52428800);   //  4 MB  [B*T][1024]
  // K-split partials overlay dead prep buffers:
  float* opart  = (float*)(w + 0);         // 16 MB  [2][32768][64] fp32
  float* mlpart = (float*)(w + 16777216);  // 512 KB [2][32768][2]  fp32

  prep_kernel<<<dim3(4096, 7), 256, 0, stream>>>(x, mem, pos, qw, kw, vw, rw, ow,
                                                 catb, posb, wqb, wkb, wvb, wrb, wob);
  gemm_qkvr<<<768, 256, 0, stream>>>(catb, posb, wqb, wrb, wkb, wvb, bu, bv,
                                     qub, qvb, rbuf, kbuf, vtb);
  attn_kernel<<<512, 256, 0, stream>>>(qub, qvb, kbuf, vtb, rbuf, opart, mlpart);
  combine_kernel<<<2048, 256, 0, stream>>>(opart, mlpart, aob);
  gemm_out<<<128, 256, 0, stream>>>(aob, wob, out);
}